// Round 1
// baseline (1685.330 us; speedup 1.0000x reference)
//
#include <hip/hip_runtime.h>
#include <hip/hip_bf16.h>
#include <stdint.h>

#define N_NODES  100000
#define N_EDGES  1600000
#define DIM      128
#define N_LAYERS 3
#define N_GRAPHS 2048

// workspace layout (bytes)
#define OFF_CNT   0            // N_NODES ints: counts, later reused as cursor
#define OFF_OFFS  400000       // (N_NODES+1) ints
#define OFF_BSUM  800128       // up to 128 ints (block sums for scan)
#define OFF_ESRC  801024       // N_EDGES ints (CSR: src ids grouped by dst)
#define OFF_BUFA  7201024      // N_NODES*DIM f32
#define OFF_BUFB  58401024     // N_NODES*DIM f32
// total ~109.6 MB

// ---------------- CSR build ----------------

__global__ void k_hist(const int* __restrict__ dst, int* __restrict__ cnt) {
    int e = blockIdx.x * 256 + threadIdx.x;   // grid is exactly N_EDGES/256
    atomicAdd(&cnt[dst[e]], 1);
}

__global__ void k_scanA(const int* __restrict__ cnt, int* __restrict__ bsum) {
    __shared__ int s[256];
    int t  = threadIdx.x;
    int i0 = blockIdx.x * 1024 + t * 4;
    int sum = 0;
#pragma unroll
    for (int j = 0; j < 4; j++) { int i = i0 + j; if (i < N_NODES) sum += cnt[i]; }
    s[t] = sum; __syncthreads();
    for (int off = 128; off > 0; off >>= 1) { if (t < off) s[t] += s[t + off]; __syncthreads(); }
    if (t == 0) bsum[blockIdx.x] = s[0];
}

__global__ void k_scanB(int* __restrict__ bsum, int nb) {
    if (threadIdx.x == 0) {
        int run = 0;
        for (int i = 0; i < nb; i++) { int v = bsum[i]; bsum[i] = run; run += v; }
    }
}

// counts -> exclusive offsets; also initialize cursor (aliases cnt buffer: all
// reads of cnt happen before the first barrier, all writes after the last).
__global__ void k_scanC(const int* __restrict__ cnt, const int* __restrict__ bsumX,
                        int* __restrict__ offs, int* __restrict__ cursor) {
    __shared__ int s[256];
    int t  = threadIdx.x;
    int i0 = blockIdx.x * 1024 + t * 4;
    int c[4];
#pragma unroll
    for (int j = 0; j < 4; j++) { int i = i0 + j; c[j] = (i < N_NODES) ? cnt[i] : 0; }
    int sum = c[0] + c[1] + c[2] + c[3];
    s[t] = sum; __syncthreads();
    for (int off = 1; off < 256; off <<= 1) {
        int v = (t >= off) ? s[t - off] : 0;
        __syncthreads();
        s[t] += v;
        __syncthreads();
    }
    int excl = s[t] - sum;
    int run  = bsumX[blockIdx.x] + excl;
#pragma unroll
    for (int j = 0; j < 4; j++) {
        int i = i0 + j;
        if (i < N_NODES) { offs[i] = run; cursor[i] = run; run += c[j]; }
    }
    if (blockIdx.x == 0 && t == 0) offs[N_NODES] = N_EDGES;
}

__global__ void k_scatter(const int* __restrict__ src, const int* __restrict__ dst,
                          int* __restrict__ cursor, int* __restrict__ esrc) {
    int e = blockIdx.x * 256 + threadIdx.x;
    int d = dst[e];
    int pos = atomicAdd(&cursor[d], 1);
    esrc[pos] = src[e];
}

// ---------------- aggregation: out[i] = x[i] + sum_{e in CSR(i)} x[esrc[e]] ----------------

__global__ void k_agg(const float* __restrict__ x, const int* __restrict__ offs,
                      const int* __restrict__ esrc, float* __restrict__ out) {
    int tid  = threadIdx.x;
    int node = blockIdx.x * 2 + (tid >> 7);
    int d    = tid & 127;
    int e0 = offs[node], e1 = offs[node + 1];
    float acc = x[(size_t)node * DIM + d];
    for (int e = e0; e < e1; ++e) {
        int s = esrc[e];
        acc += x[(size_t)s * DIM + d];
    }
    out[(size_t)node * DIM + d] = acc;
}

// ---------------- fused MLP: out = relu(relu(in@W1+b1)@W2+b2), in-place safe ----------------

#define RTPAD 36   // padded row stride of transposed tile (36*4B=144B, 16B-aligned, breaks bank conflicts)

__global__ __launch_bounds__(256) void k_mlp(const float* __restrict__ in, float* __restrict__ out,
                                             const float* __restrict__ W1, const float* __restrict__ b1,
                                             const float* __restrict__ W2, const float* __restrict__ b2) {
    __shared__ __align__(16) float W1s[DIM * DIM];
    __shared__ __align__(16) float W2s[DIM * DIM];
    __shared__ __align__(16) float rowT[DIM * RTPAD];
    __shared__ float b1s[DIM], b2s[DIM];

    int tid = threadIdx.x;
    for (int i = tid * 4; i < DIM * DIM; i += 1024) {
        *(float4*)&W1s[i] = *(const float4*)&W1[i];
        *(float4*)&W2s[i] = *(const float4*)&W2[i];
    }
    if (tid < DIM) { b1s[tid] = b1[tid]; b2s[tid] = b2[tid]; }

    int row0 = blockIdx.x * 32;           // grid is exactly N_NODES/32
    for (int idx = tid; idx < 32 * DIM; idx += 256) {
        int r = idx >> 7, k = idx & 127;
        rowT[k * RTPAD + r] = in[(size_t)(row0 + r) * DIM + k];
    }
    __syncthreads();

    int cq = tid & 31, rq = tid >> 5;     // 32 col-groups x 8 row-groups
    int c0 = cq * 4, r0 = rq * 4;

    float acc[4][4];
#pragma unroll
    for (int i = 0; i < 4; i++)
#pragma unroll
        for (int j = 0; j < 4; j++) acc[i][j] = 0.f;

#pragma unroll 4
    for (int k = 0; k < DIM; k++) {
        float4 a = *(float4*)&rowT[k * RTPAD + r0];
        float4 w = *(float4*)&W1s[k * DIM + c0];
        float av[4] = {a.x, a.y, a.z, a.w};
        float wv[4] = {w.x, w.y, w.z, w.w};
#pragma unroll
        for (int i = 0; i < 4; i++)
#pragma unroll
            for (int j = 0; j < 4; j++) acc[i][j] += av[i] * wv[j];
    }
    __syncthreads();   // all rowT reads done before overwrite

    float t4[4][4];
#pragma unroll
    for (int i = 0; i < 4; i++)
#pragma unroll
        for (int j = 0; j < 4; j++) t4[i][j] = fmaxf(acc[i][j] + b1s[c0 + j], 0.f);
#pragma unroll
    for (int i = 0; i < 4; i++)
#pragma unroll
        for (int j = 0; j < 4; j++) rowT[(c0 + j) * RTPAD + (r0 + i)] = t4[i][j];

#pragma unroll
    for (int i = 0; i < 4; i++)
#pragma unroll
        for (int j = 0; j < 4; j++) acc[i][j] = 0.f;
    __syncthreads();

#pragma unroll 4
    for (int k = 0; k < DIM; k++) {
        float4 a = *(float4*)&rowT[k * RTPAD + r0];
        float4 w = *(float4*)&W2s[k * DIM + c0];
        float av[4] = {a.x, a.y, a.z, a.w};
        float wv[4] = {w.x, w.y, w.z, w.w};
#pragma unroll
        for (int i = 0; i < 4; i++)
#pragma unroll
            for (int j = 0; j < 4; j++) acc[i][j] += av[i] * wv[j];
    }

#pragma unroll
    for (int i = 0; i < 4; i++) {
        float4 o;
        o.x = fmaxf(acc[i][0] + b2s[c0 + 0], 0.f);
        o.y = fmaxf(acc[i][1] + b2s[c0 + 1], 0.f);
        o.z = fmaxf(acc[i][2] + b2s[c0 + 2], 0.f);
        o.w = fmaxf(acc[i][3] + b2s[c0 + 3], 0.f);
        *(float4*)&out[(size_t)(row0 + r0 + i) * DIM + c0] = o;
    }
}

// ---------------- pool: segmented mean over sorted batch ids ----------------

__global__ void k_pool(const float* __restrict__ xf, const int* __restrict__ batch,
                       float* __restrict__ out) {
    int g = blockIdx.x;
    int d = threadIdx.x;
    int lo = 0, hi = N_NODES;
    while (lo < hi) { int m = (lo + hi) >> 1; if (batch[m] < g) lo = m + 1; else hi = m; }
    int start = lo;
    hi = N_NODES;
    while (lo < hi) { int m = (lo + hi) >> 1; if (batch[m] <= g) lo = m + 1; else hi = m; }
    int end = lo;
    float acc = 0.f;
    for (int i = start; i < end; i++) acc += xf[(size_t)i * DIM + d];
    float cntf = (float)(end - start);
    out[(size_t)g * DIM + d] = acc / fmaxf(cntf, 1.f);
}

// ---------------- launch ----------------

extern "C" void kernel_launch(void* const* d_in, const int* in_sizes, int n_in,
                              void* d_out, int out_size, void* d_ws, size_t ws_size,
                              hipStream_t stream) {
    const float* x    = (const float*)d_in[0];
    const int*   ei   = (const int*)d_in[1];
    const int*   batch= (const int*)d_in[2];
    const float* W1   = (const float*)d_in[3];
    const float* b1   = (const float*)d_in[4];
    const float* W2   = (const float*)d_in[5];
    const float* b2   = (const float*)d_in[6];
    const int* src = ei;
    const int* dst = ei + N_EDGES;

    char*  ws   = (char*)d_ws;
    int*   cnt  = (int*)(ws + OFF_CNT);     // counts, then cursor
    int*   offs = (int*)(ws + OFF_OFFS);
    int*   bsum = (int*)(ws + OFF_BSUM);
    int*   esrc = (int*)(ws + OFF_ESRC);
    float* bufA = (float*)(ws + OFF_BUFA);
    float* bufB = (float*)(ws + OFF_BUFB);
    float* outp = (float*)d_out;

    // CSR build (edge_index is identical for all layers)
    hipMemsetAsync(cnt, 0, N_NODES * sizeof(int), stream);
    k_hist<<<N_EDGES / 256, 256, 0, stream>>>(dst, cnt);
    k_scanA<<<98, 256, 0, stream>>>(cnt, bsum);
    k_scanB<<<1, 64, 0, stream>>>(bsum, 98);
    k_scanC<<<98, 256, 0, stream>>>(cnt, bsum, offs, cnt);
    k_scatter<<<N_EDGES / 256, 256, 0, stream>>>(src, dst, cnt, esrc);

    // 3 GIN layers
    const float* xin = x;
    for (int l = 0; l < N_LAYERS; ++l) {
        float* aggbuf = (l == 1) ? bufB : bufA;   // l0->A, l1->B, l2->A
        k_agg<<<N_NODES / 2, 256, 0, stream>>>(xin, offs, esrc, aggbuf);
        k_mlp<<<N_NODES / 32, 256, 0, stream>>>(aggbuf, aggbuf,
                                                W1 + (size_t)l * DIM * DIM, b1 + (size_t)l * DIM,
                                                W2 + (size_t)l * DIM * DIM, b2 + (size_t)l * DIM);
        xin = aggbuf;
    }

    // global mean pool
    k_pool<<<N_GRAPHS, 128, 0, stream>>>(xin, batch, outp);
}

// Round 2
// 527.359 us; speedup vs baseline: 3.1958x; 3.1958x over previous
//
#include <hip/hip_runtime.h>
#include <hip/hip_bf16.h>
#include <stdint.h>

#define N_NODES  100000
#define N_PAD    100032          // padded to multiple of 64 for MLP tiles
#define N_EDGES  1600000
#define DIM      128
#define N_LAYERS 3
#define N_GRAPHS 2048

typedef _Float16 f16;
typedef __attribute__((ext_vector_type(2))) _Float16 f16x2;
typedef __attribute__((ext_vector_type(8))) _Float16 f16x8;
typedef __attribute__((ext_vector_type(4))) float f32x4;

#define MFMA16(a, b, c) __builtin_amdgcn_mfma_f32_16x16x32_f16((a), (b), (c), 0, 0, 0)

// workspace layout (bytes)
#define OFF_CNT   0u             // N_NODES ints (counts, later cursor)
#define OFF_OFFS  400000u        // N_NODES+1 ints
#define OFF_BSUM  800128u        // block sums for scan
#define OFF_ESRC  801024u        // N_EDGES ints
#define OFF_X16   7201024u       // N_PAD*DIM f16
#define OFF_A16   32809216u      // N_PAD*DIM f16
#define OFF_B16   58417408u      // N_PAD*DIM f16
#define OFF_W1T   84025600u      // 3*128*128 f16 (transposed: [l][n][k])
#define OFF_W2T   84123904u      // 3*128*128 f16
// end ~84.2 MB

// ---------------- CSR build ----------------

__global__ void k_hist(const int* __restrict__ dst, int* __restrict__ cnt) {
    int e = blockIdx.x * 256 + threadIdx.x;
    atomicAdd(&cnt[dst[e]], 1);
}

__global__ void k_scanA(const int* __restrict__ cnt, int* __restrict__ bsum) {
    __shared__ int s[256];
    int t = threadIdx.x;
    int i0 = blockIdx.x * 1024 + t * 4;
    int sum = 0;
#pragma unroll
    for (int j = 0; j < 4; j++) { int i = i0 + j; if (i < N_NODES) sum += cnt[i]; }
    s[t] = sum; __syncthreads();
    for (int off = 128; off > 0; off >>= 1) { if (t < off) s[t] += s[t + off]; __syncthreads(); }
    if (t == 0) bsum[blockIdx.x] = s[0];
}

__global__ void k_scanB(int* __restrict__ bsum, int nb) {
    if (threadIdx.x == 0) {
        int run = 0;
        for (int i = 0; i < nb; i++) { int v = bsum[i]; bsum[i] = run; run += v; }
    }
}

__global__ void k_scanC(const int* __restrict__ cnt, const int* __restrict__ bsumX,
                        int* __restrict__ offs, int* __restrict__ cursor) {
    __shared__ int s[256];
    int t = threadIdx.x;
    int i0 = blockIdx.x * 1024 + t * 4;
    int c[4];
#pragma unroll
    for (int j = 0; j < 4; j++) { int i = i0 + j; c[j] = (i < N_NODES) ? cnt[i] : 0; }
    int sum = c[0] + c[1] + c[2] + c[3];
    s[t] = sum; __syncthreads();
    for (int off = 1; off < 256; off <<= 1) {
        int v = (t >= off) ? s[t - off] : 0;
        __syncthreads();
        s[t] += v;
        __syncthreads();
    }
    int excl = s[t] - sum;
    int run = bsumX[blockIdx.x] + excl;
#pragma unroll
    for (int j = 0; j < 4; j++) {
        int i = i0 + j;
        if (i < N_NODES) { offs[i] = run; cursor[i] = run; run += c[j]; }
    }
    if (blockIdx.x == 0 && t == 0) offs[N_NODES] = N_EDGES;
}

__global__ void k_scatter(const int* __restrict__ src, const int* __restrict__ dst,
                          int* __restrict__ cursor, int* __restrict__ esrc) {
    int e = blockIdx.x * 256 + threadIdx.x;
    int d = dst[e];
    int pos = atomicAdd(&cursor[d], 1);
    esrc[pos] = src[e];
}

// ---------------- dtype conversion ----------------

__global__ void k_cvtX(const float* __restrict__ x, f16* __restrict__ o) {
    size_t i = ((size_t)blockIdx.x * 256 + threadIdx.x) * 8;
    float4 v0 = *(const float4*)&x[i];
    float4 v1 = *(const float4*)&x[i + 4];
    f16x8 h;
    h[0] = (f16)v0.x; h[1] = (f16)v0.y; h[2] = (f16)v0.z; h[3] = (f16)v0.w;
    h[4] = (f16)v1.x; h[5] = (f16)v1.y; h[6] = (f16)v1.z; h[7] = (f16)v1.w;
    *(f16x8*)&o[i] = h;
}

// W: [3][k][n] f32 row-major -> Wt: [3][n][k] f16
__global__ void k_cvtW(const float* __restrict__ W, f16* __restrict__ Wt) {
    int t = blockIdx.x * 256 + threadIdx.x;     // 49152 total
    int l = t >> 14;
    int kn = t & 16383;
    int k = kn >> 7, n = kn & 127;
    Wt[l * 16384 + n * 128 + k] = (f16)W[t];
}

// ---------------- aggregation: out[i] = x[i] + sum_{j in N(i)} x[j]  (f16 in, f16 out)

__global__ __launch_bounds__(256) void k_agg(const f16* __restrict__ x, const int* __restrict__ offs,
                                             const int* __restrict__ esrc, f16* __restrict__ out) {
    int tid = threadIdx.x;
    int node = blockIdx.x * 4 + (tid >> 6);
    if (node >= N_NODES) return;
    int lane = tid & 63;
    const f16x2* xr = (const f16x2*)x;          // 64 words per row
    int e0 = offs[node], e1 = offs[node + 1];
    f16x2 sv = xr[(size_t)node * 64 + lane];
    float a0 = (float)sv[0], a1 = (float)sv[1];
    int e = e0;
    for (; e + 4 <= e1; e += 4) {
        int s0 = esrc[e], s1 = esrc[e + 1], s2 = esrc[e + 2], s3 = esrc[e + 3];
        f16x2 v0 = xr[(size_t)s0 * 64 + lane];
        f16x2 v1 = xr[(size_t)s1 * 64 + lane];
        f16x2 v2 = xr[(size_t)s2 * 64 + lane];
        f16x2 v3 = xr[(size_t)s3 * 64 + lane];
        a0 += (float)v0[0] + (float)v1[0] + (float)v2[0] + (float)v3[0];
        a1 += (float)v0[1] + (float)v1[1] + (float)v2[1] + (float)v3[1];
    }
    for (; e < e1; e++) {
        f16x2 v = xr[(size_t)esrc[e] * 64 + lane];
        a0 += (float)v[0]; a1 += (float)v[1];
    }
    f16x2 o; o[0] = (f16)a0; o[1] = (f16)a1;
    ((f16x2*)out)[(size_t)node * 64 + lane] = o;
}

// ---------------- fused MFMA MLP: out = relu(relu(in@W1+b1)@W2+b2), f16 io, in-place safe

#define BM 64
#define LDS_K 136    // padded row stride in f16 elems (272 B): bank-balanced for b128 reads

__global__ __launch_bounds__(256) void k_mlp(const f16* __restrict__ in, f16* __restrict__ out,
                                             const f16* __restrict__ W1t, const float* __restrict__ b1,
                                             const f16* __restrict__ W2t, const float* __restrict__ b2) {
    __shared__ __align__(16) f16 tile[BM * LDS_K];
    int tid = threadIdx.x;
    int lane = tid & 63;
    int w = tid >> 6;                 // wave 0..3, owns cols [w*32, w*32+32)
    int fr = lane & 15;               // fragment row index (m for A, n for B, col for D)
    int fg = lane >> 4;               // k-group 0..3
    int row0 = blockIdx.x * BM;

    // B fragments (W1t/W2t are [n][k] f16) held in registers for the whole block
    f16x8 w1f[2][4], w2f[2][4];
    float b1v[2], b2v[2];
#pragma unroll
    for (int nt = 0; nt < 2; nt++) {
        int col = w * 32 + nt * 16 + fr;
#pragma unroll
        for (int ks = 0; ks < 4; ks++) {
            int k = ks * 32 + fg * 8;
            w1f[nt][ks] = *(const f16x8*)&W1t[col * DIM + k];
            w2f[nt][ks] = *(const f16x8*)&W2t[col * DIM + k];
        }
        b1v[nt] = b1[col];
        b2v[nt] = b2[col];
    }

    // stage input tile: 64 rows x 256 B, coalesced
#pragma unroll
    for (int p = 0; p < 4; p++) {
        int idx = p * 256 + tid;
        int r = idx >> 4, c = idx & 15;
        *(float4*)&tile[r * LDS_K + c * 8] = *(const float4*)&in[(size_t)(row0 + r) * DIM + c * 8];
    }
    __syncthreads();

    // GEMM1: H = relu(X @ W1 + b1)
    f32x4 acc[4][2];
#pragma unroll
    for (int mt = 0; mt < 4; mt++)
#pragma unroll
        for (int nt = 0; nt < 2; nt++) acc[mt][nt] = (f32x4){0.f, 0.f, 0.f, 0.f};

#pragma unroll
    for (int mt = 0; mt < 4; mt++) {
#pragma unroll
        for (int ks = 0; ks < 4; ks++) {
            f16x8 a = *(const f16x8*)&tile[(mt * 16 + fr) * LDS_K + ks * 32 + fg * 8];
            acc[mt][0] = MFMA16(a, w1f[0][ks], acc[mt][0]);
            acc[mt][1] = MFMA16(a, w1f[1][ks], acc[mt][1]);
        }
    }
    __syncthreads();   // all X reads done before overwriting with H

#pragma unroll
    for (int mt = 0; mt < 4; mt++)
#pragma unroll
        for (int nt = 0; nt < 2; nt++) {
            int col = w * 32 + nt * 16 + fr;
#pragma unroll
            for (int r = 0; r < 4; r++) {
                int m = mt * 16 + fg * 4 + r;
                tile[m * LDS_K + col] = (f16)fmaxf(acc[mt][nt][r] + b1v[nt], 0.f);
            }
        }
    __syncthreads();

    // GEMM2: OUT = relu(H @ W2 + b2)
    f32x4 acc2[4][2];
#pragma unroll
    for (int mt = 0; mt < 4; mt++)
#pragma unroll
        for (int nt = 0; nt < 2; nt++) acc2[mt][nt] = (f32x4){0.f, 0.f, 0.f, 0.f};

#pragma unroll
    for (int mt = 0; mt < 4; mt++) {
#pragma unroll
        for (int ks = 0; ks < 4; ks++) {
            f16x8 a = *(const f16x8*)&tile[(mt * 16 + fr) * LDS_K + ks * 32 + fg * 8];
            acc2[mt][0] = MFMA16(a, w2f[0][ks], acc2[mt][0]);
            acc2[mt][1] = MFMA16(a, w2f[1][ks], acc2[mt][1]);
        }
    }
    __syncthreads();   // all H reads done

#pragma unroll
    for (int mt = 0; mt < 4; mt++)
#pragma unroll
        for (int nt = 0; nt < 2; nt++) {
            int col = w * 32 + nt * 16 + fr;
#pragma unroll
            for (int r = 0; r < 4; r++) {
                int m = mt * 16 + fg * 4 + r;
                tile[m * LDS_K + col] = (f16)fmaxf(acc2[mt][nt][r] + b2v[nt], 0.f);
            }
        }
    __syncthreads();

    // coalesced store of the 64x128 f16 output tile
#pragma unroll
    for (int p = 0; p < 4; p++) {
        int idx = p * 256 + tid;
        int r = idx >> 4, c = idx & 15;
        *(float4*)&out[(size_t)(row0 + r) * DIM + c * 8] = *(float4*)&tile[r * LDS_K + c * 8];
    }
}

// ---------------- pool: segmented mean over sorted batch ids ----------------

__global__ void k_pool(const f16* __restrict__ xf, const int* __restrict__ batch,
                       float* __restrict__ out) {
    int g = blockIdx.x;
    int d = threadIdx.x;
    int lo = 0, hi = N_NODES;
    while (lo < hi) { int m = (lo + hi) >> 1; if (batch[m] < g) lo = m + 1; else hi = m; }
    int start = lo;
    hi = N_NODES;
    while (lo < hi) { int m = (lo + hi) >> 1; if (batch[m] <= g) lo = m + 1; else hi = m; }
    int end = lo;
    float acc = 0.f;
    for (int i = start; i < end; i++) acc += (float)xf[(size_t)i * DIM + d];
    float cntf = (float)(end - start);
    out[(size_t)g * DIM + d] = acc / fmaxf(cntf, 1.f);
}

// ---------------- launch ----------------

extern "C" void kernel_launch(void* const* d_in, const int* in_sizes, int n_in,
                              void* d_out, int out_size, void* d_ws, size_t ws_size,
                              hipStream_t stream) {
    const float* x     = (const float*)d_in[0];
    const int*   ei    = (const int*)d_in[1];
    const int*   batch = (const int*)d_in[2];
    const float* W1    = (const float*)d_in[3];
    const float* b1    = (const float*)d_in[4];
    const float* W2    = (const float*)d_in[5];
    const float* b2    = (const float*)d_in[6];
    const int* src = ei;
    const int* dst = ei + N_EDGES;

    char* ws = (char*)d_ws;
    int*   cnt  = (int*)(ws + OFF_CNT);
    int*   offs = (int*)(ws + OFF_OFFS);
    int*   bsum = (int*)(ws + OFF_BSUM);
    int*   esrc = (int*)(ws + OFF_ESRC);
    f16*   x16  = (f16*)(ws + OFF_X16);
    f16*   a16  = (f16*)(ws + OFF_A16);
    f16*   b16  = (f16*)(ws + OFF_B16);
    f16*   w1t  = (f16*)(ws + OFF_W1T);
    f16*   w2t  = (f16*)(ws + OFF_W2T);
    float* outp = (float*)d_out;

    // CSR build (edge_index identical across layers)
    hipMemsetAsync(cnt, 0, N_NODES * sizeof(int), stream);
    k_hist<<<N_EDGES / 256, 256, 0, stream>>>(dst, cnt);
    k_scanA<<<98, 256, 0, stream>>>(cnt, bsum);
    k_scanB<<<1, 64, 0, stream>>>(bsum, 98);
    k_scanC<<<98, 256, 0, stream>>>(cnt, bsum, offs, cnt);
    k_scatter<<<N_EDGES / 256, 256, 0, stream>>>(src, dst, cnt, esrc);

    // conversions
    k_cvtX<<<6250, 256, 0, stream>>>(x, x16);                  // 100000*128/8/256
    k_cvtW<<<192, 256, 0, stream>>>(W1, w1t);
    k_cvtW<<<192, 256, 0, stream>>>(W2, w2t);
    // keep MLP pad rows deterministic
    hipMemsetAsync(a16 + (size_t)N_NODES * DIM, 0, (size_t)(N_PAD - N_NODES) * DIM * sizeof(f16), stream);
    hipMemsetAsync(b16 + (size_t)N_NODES * DIM, 0, (size_t)(N_PAD - N_NODES) * DIM * sizeof(f16), stream);

    // 3 GIN layers
    const f16* xin = x16;
    for (int l = 0; l < N_LAYERS; ++l) {
        f16* aggbuf = (l == 1) ? b16 : a16;    // l0->A, l1->B, l2->A
        k_agg<<<(N_NODES + 3) / 4, 256, 0, stream>>>(xin, offs, esrc, aggbuf);
        k_mlp<<<N_PAD / BM, 256, 0, stream>>>(aggbuf, aggbuf,
                                              w1t + (size_t)l * DIM * DIM, b1 + (size_t)l * DIM,
                                              w2t + (size_t)l * DIM * DIM, b2 + (size_t)l * DIM);
        xin = aggbuf;
    }

    // global mean pool (f32 accumulate, f32 out)
    k_pool<<<N_GRAPHS, 128, 0, stream>>>(xin, batch, outp);
}

// Round 3
// 351.279 us; speedup vs baseline: 4.7977x; 1.5013x over previous
//
#include <hip/hip_runtime.h>
#include <hip/hip_bf16.h>
#include <stdint.h>

#define N_NODES  100000
#define N_PAD    100032          // padded to multiple of 64 for MLP tiles
#define N_EDGES  1600000
#define DIM      128
#define N_LAYERS 3
#define N_GRAPHS 2048

#define BSHIFT   9               // bucket = 512 consecutive dst nodes
#define NBUCKET  196             // ceil(N_NODES / 512)
#define P1CHUNK  8192
#define P1GRID   196             // ceil(N_EDGES / P1CHUNK)

typedef _Float16 f16;
typedef __attribute__((ext_vector_type(2))) _Float16 f16x2;
typedef __attribute__((ext_vector_type(8))) _Float16 f16x8;
typedef __attribute__((ext_vector_type(4))) float f32x4;

#define MFMA16(a, b, c) __builtin_amdgcn_mfma_f32_16x16x32_f16((a), (b), (c), 0, 0, 0)

// ---------------- workspace layout (bytes, all 64B-aligned) ----------------
#define OFF_OFFS  0u             // (N_NODES+1) ints
#define OFF_BHT   400064u        // NBUCKET ints (bucket totals)
#define OFF_BST   400896u        // NBUCKET+1 ints (bucket starts)
#define OFF_GCUR  401728u        // NBUCKET ints (bucket cursors)
#define OFF_BLKH  402560u        // P1GRID*NBUCKET ints (per-block bucket hist)
#define OFF_ESRC  556288u        // N_EDGES ints
#define OFF_PAIR  6956288u       // N_EDGES uint2 (dst,src)
#define OFF_X16   19756288u      // N_PAD*DIM f16
#define OFF_A16   45364480u      // N_PAD*DIM f16
#define OFF_B16   70972672u      // N_PAD*DIM f16
#define OFF_W1T   96580864u      // 3*128*128 f16 ([l][n][k])
#define OFF_W2T   96679168u      // 3*128*128 f16
// end ~96.8 MB

// ---------------- CSR build: bucket partition ----------------

__global__ __launch_bounds__(256) void k_bhist(const int* __restrict__ dst,
                                               int* __restrict__ btot, int* __restrict__ blkh) {
    __shared__ int h[NBUCKET];
    int tid = threadIdx.x, b = blockIdx.x;
    if (tid < NBUCKET) h[tid] = 0;
    __syncthreads();
    int base = b * P1CHUNK;
    int n = min(P1CHUNK, N_EDGES - base);
    for (int i = tid; i < n; i += 256)
        atomicAdd(&h[dst[base + i] >> BSHIFT], 1);
    __syncthreads();
    if (tid < NBUCKET) {
        blkh[b * NBUCKET + tid] = h[tid];
        atomicAdd(&btot[tid], h[tid]);
    }
}

__global__ void k_bscan(const int* __restrict__ btot, int* __restrict__ bstart,
                        int* __restrict__ gcursor, int* __restrict__ offs) {
    __shared__ int s[NBUCKET + 1];
    if (threadIdx.x == 0) {
        int run = 0;
        for (int i = 0; i < NBUCKET; i++) { s[i] = run; run += btot[i]; }
        s[NBUCKET] = run;
    }
    __syncthreads();
    int t = threadIdx.x;
    if (t <= NBUCKET) bstart[t] = s[t];
    if (t < NBUCKET)  gcursor[t] = s[t];
    if (t == 0) offs[N_NODES] = N_EDGES;
}

__global__ __launch_bounds__(256) void k_part1(const int* __restrict__ src, const int* __restrict__ dst,
                                               const int* __restrict__ blkh, int* __restrict__ gcursor,
                                               uint2* __restrict__ pairs) {
    __shared__ int gbase[NBUCKET];
    __shared__ int cur[NBUCKET];
    int tid = threadIdx.x, b = blockIdx.x;
    if (tid < NBUCKET) {
        int h = blkh[b * NBUCKET + tid];
        gbase[tid] = atomicAdd(&gcursor[tid], h);
        cur[tid] = 0;
    }
    __syncthreads();
    int base = b * P1CHUNK;
    int n = min(P1CHUNK, N_EDGES - base);
    for (int i = tid; i < n; i += 256) {
        int d = dst[base + i], s = src[base + i];
        int bin = d >> BSHIFT;
        int slot = atomicAdd(&cur[bin], 1);
        uint2 p; p.x = (unsigned)d; p.y = (unsigned)s;
        pairs[gbase[bin] + slot] = p;     // lines exclusively written by this block
    }
}

__global__ __launch_bounds__(256) void k_part2(const uint2* __restrict__ pairs,
                                               const int* __restrict__ bstart,
                                               int* __restrict__ offs, int* __restrict__ esrc) {
    __shared__ int cnt[512];
    __shared__ int excl[512];
    __shared__ int sc[256];
    int t = threadIdx.x, b = blockIdx.x;
    int n0 = b << BSHIFT;
    int nn = min(512, N_NODES - n0);
    int e0 = bstart[b], e1 = bstart[b + 1];
    cnt[t] = 0; cnt[t + 256] = 0;
    __syncthreads();
    for (int i = e0 + t; i < e1; i += 256)
        atomicAdd(&cnt[pairs[i].x & 511], 1);
    __syncthreads();
    int a = cnt[2 * t], psum = a + cnt[2 * t + 1];
    sc[t] = psum;
    __syncthreads();
    for (int off = 1; off < 256; off <<= 1) {
        int v = (t >= off) ? sc[t - off] : 0;
        __syncthreads();
        sc[t] += v;
        __syncthreads();
    }
    int pairExcl = sc[t] - psum;
    excl[2 * t] = pairExcl;
    excl[2 * t + 1] = pairExcl + a;
    __syncthreads();
    for (int j = t; j < nn; j += 256) offs[n0 + j] = e0 + excl[j];
    __syncthreads();   // offs written (reads of excl done) before cursor mutation
    for (int i = e0 + t; i < e1; i += 256) {
        uint2 p = pairs[i];
        int pos = e0 + atomicAdd(&excl[p.x & 511], 1);
        esrc[pos] = (int)p.y;              // 32KB region, single block -> single XCD
    }
}

// ---------------- dtype conversion ----------------

__global__ void k_cvtX(const float* __restrict__ x, f16* __restrict__ o) {
    size_t i = ((size_t)blockIdx.x * 256 + threadIdx.x) * 8;
    float4 v0 = *(const float4*)&x[i];
    float4 v1 = *(const float4*)&x[i + 4];
    f16x8 h;
    h[0] = (f16)v0.x; h[1] = (f16)v0.y; h[2] = (f16)v0.z; h[3] = (f16)v0.w;
    h[4] = (f16)v1.x; h[5] = (f16)v1.y; h[6] = (f16)v1.z; h[7] = (f16)v1.w;
    *(f16x8*)&o[i] = h;
}

// W: [3][k][n] f32 -> Wt: [3][n][k] f16
__global__ void k_cvtW(const float* __restrict__ W, f16* __restrict__ Wt) {
    int t = blockIdx.x * 256 + threadIdx.x;
    int l = t >> 14;
    int kn = t & 16383;
    int k = kn >> 7, n = kn & 127;
    Wt[l * 16384 + n * 128 + k] = (f16)W[t];
}

// ---------------- aggregation: out[i] = x[i] + sum_{j in N(i)} x[j] ----------------
// 1 wave per node; 4 lane-groups of 16 process 4 edges concurrently, 16B loads.

__global__ __launch_bounds__(256) void k_agg(const f16* __restrict__ x, const int* __restrict__ offs,
                                             const int* __restrict__ esrc, f16* __restrict__ out) {
    int tid = threadIdx.x;
    int node = blockIdx.x * 4 + (tid >> 6);
    int lane = tid & 63;
    int g = lane >> 4;                  // edge group 0..3
    int c = lane & 15;                  // 16B column: dims [c*8, c*8+8)
    const f16x8* xr = (const f16x8*)x;  // 16 chunks per row
    int e0 = offs[node], e1 = offs[node + 1];

    float acc[8];
    f16x8 sv = xr[(size_t)node * 16 + c];
#pragma unroll
    for (int j = 0; j < 8; j++) acc[j] = (g == 0) ? (float)sv[j] : 0.f;

    int e = e0 + g;
    for (; e + 4 < e1; e += 8) {        // 2 edges per group in flight
        int s0 = esrc[e], s1 = esrc[e + 4];
        f16x8 v0 = xr[(size_t)s0 * 16 + c];
        f16x8 v1 = xr[(size_t)s1 * 16 + c];
#pragma unroll
        for (int j = 0; j < 8; j++) acc[j] += (float)v0[j] + (float)v1[j];
    }
    if (e < e1) {
        f16x8 v = xr[(size_t)esrc[e] * 16 + c];
#pragma unroll
        for (int j = 0; j < 8; j++) acc[j] += (float)v[j];
    }

    // combine the 4 edge groups (lanes 16 and 32 apart hold same dims)
#pragma unroll
    for (int j = 0; j < 8; j++) {
        acc[j] += __shfl_xor(acc[j], 16);
        acc[j] += __shfl_xor(acc[j], 32);
    }
    if (g == 0) {
        f16x8 o;
#pragma unroll
        for (int j = 0; j < 8; j++) o[j] = (f16)acc[j];
        ((f16x8*)out)[(size_t)node * 16 + c] = o;
    }
}

// ---------------- fused MFMA MLP: out = relu(relu(in@W1+b1)@W2+b2) ----------------

#define BM 64
#define LDS_K 136

__global__ __launch_bounds__(256) void k_mlp(const f16* __restrict__ in, f16* __restrict__ out,
                                             const f16* __restrict__ W1t, const float* __restrict__ b1,
                                             const f16* __restrict__ W2t, const float* __restrict__ b2) {
    __shared__ __align__(16) f16 tile[BM * LDS_K];
    int tid = threadIdx.x;
    int lane = tid & 63;
    int w = tid >> 6;
    int fr = lane & 15;
    int fg = lane >> 4;
    int row0 = blockIdx.x * BM;

    f16x8 w1f[2][4], w2f[2][4];
    float b1v[2], b2v[2];
#pragma unroll
    for (int nt = 0; nt < 2; nt++) {
        int col = w * 32 + nt * 16 + fr;
#pragma unroll
        for (int ks = 0; ks < 4; ks++) {
            int k = ks * 32 + fg * 8;
            w1f[nt][ks] = *(const f16x8*)&W1t[col * DIM + k];
            w2f[nt][ks] = *(const f16x8*)&W2t[col * DIM + k];
        }
        b1v[nt] = b1[col];
        b2v[nt] = b2[col];
    }

#pragma unroll
    for (int p = 0; p < 4; p++) {
        int idx = p * 256 + tid;
        int r = idx >> 4, c = idx & 15;
        *(float4*)&tile[r * LDS_K + c * 8] = *(const float4*)&in[(size_t)(row0 + r) * DIM + c * 8];
    }
    __syncthreads();

    f32x4 acc[4][2];
#pragma unroll
    for (int mt = 0; mt < 4; mt++)
#pragma unroll
        for (int nt = 0; nt < 2; nt++) acc[mt][nt] = (f32x4){0.f, 0.f, 0.f, 0.f};

#pragma unroll
    for (int mt = 0; mt < 4; mt++) {
#pragma unroll
        for (int ks = 0; ks < 4; ks++) {
            f16x8 a = *(const f16x8*)&tile[(mt * 16 + fr) * LDS_K + ks * 32 + fg * 8];
            acc[mt][0] = MFMA16(a, w1f[0][ks], acc[mt][0]);
            acc[mt][1] = MFMA16(a, w1f[1][ks], acc[mt][1]);
        }
    }
    __syncthreads();

#pragma unroll
    for (int mt = 0; mt < 4; mt++)
#pragma unroll
        for (int nt = 0; nt < 2; nt++) {
            int col = w * 32 + nt * 16 + fr;
#pragma unroll
            for (int r = 0; r < 4; r++) {
                int m = mt * 16 + fg * 4 + r;
                tile[m * LDS_K + col] = (f16)fmaxf(acc[mt][nt][r] + b1v[nt], 0.f);
            }
        }
    __syncthreads();

    f32x4 acc2[4][2];
#pragma unroll
    for (int mt = 0; mt < 4; mt++)
#pragma unroll
        for (int nt = 0; nt < 2; nt++) acc2[mt][nt] = (f32x4){0.f, 0.f, 0.f, 0.f};

#pragma unroll
    for (int mt = 0; mt < 4; mt++) {
#pragma unroll
        for (int ks = 0; ks < 4; ks++) {
            f16x8 a = *(const f16x8*)&tile[(mt * 16 + fr) * LDS_K + ks * 32 + fg * 8];
            acc2[mt][0] = MFMA16(a, w2f[0][ks], acc2[mt][0]);
            acc2[mt][1] = MFMA16(a, w2f[1][ks], acc2[mt][1]);
        }
    }
    __syncthreads();

#pragma unroll
    for (int mt = 0; mt < 4; mt++)
#pragma unroll
        for (int nt = 0; nt < 2; nt++) {
            int col = w * 32 + nt * 16 + fr;
#pragma unroll
            for (int r = 0; r < 4; r++) {
                int m = mt * 16 + fg * 4 + r;
                tile[m * LDS_K + col] = (f16)fmaxf(acc2[mt][nt][r] + b2v[nt], 0.f);
            }
        }
    __syncthreads();

#pragma unroll
    for (int p = 0; p < 4; p++) {
        int idx = p * 256 + tid;
        int r = idx >> 4, c = idx & 15;
        *(float4*)&out[(size_t)(row0 + r) * DIM + c * 8] = *(float4*)&tile[r * LDS_K + c * 8];
    }
}

// ---------------- pool ----------------

__global__ void k_pool(const f16* __restrict__ xf, const int* __restrict__ batch,
                       float* __restrict__ out) {
    int g = blockIdx.x;
    int d = threadIdx.x;
    int lo = 0, hi = N_NODES;
    while (lo < hi) { int m = (lo + hi) >> 1; if (batch[m] < g) lo = m + 1; else hi = m; }
    int start = lo;
    hi = N_NODES;
    while (lo < hi) { int m = (lo + hi) >> 1; if (batch[m] <= g) lo = m + 1; else hi = m; }
    int end = lo;
    float acc = 0.f;
    for (int i = start; i < end; i++) acc += (float)xf[(size_t)i * DIM + d];
    float cntf = (float)(end - start);
    out[(size_t)g * DIM + d] = acc / fmaxf(cntf, 1.f);
}

// ---------------- launch ----------------

extern "C" void kernel_launch(void* const* d_in, const int* in_sizes, int n_in,
                              void* d_out, int out_size, void* d_ws, size_t ws_size,
                              hipStream_t stream) {
    const float* x     = (const float*)d_in[0];
    const int*   ei    = (const int*)d_in[1];
    const int*   batch = (const int*)d_in[2];
    const float* W1    = (const float*)d_in[3];
    const float* b1    = (const float*)d_in[4];
    const float* W2    = (const float*)d_in[5];
    const float* b2    = (const float*)d_in[6];
    const int* src = ei;
    const int* dst = ei + N_EDGES;

    char* ws = (char*)d_ws;
    int*   offs  = (int*)(ws + OFF_OFFS);
    int*   btot  = (int*)(ws + OFF_BHT);
    int*   bst   = (int*)(ws + OFF_BST);
    int*   gcur  = (int*)(ws + OFF_GCUR);
    int*   blkh  = (int*)(ws + OFF_BLKH);
    int*   esrc  = (int*)(ws + OFF_ESRC);
    uint2* pairs = (uint2*)(ws + OFF_PAIR);
    f16*   x16   = (f16*)(ws + OFF_X16);
    f16*   a16   = (f16*)(ws + OFF_A16);
    f16*   b16   = (f16*)(ws + OFF_B16);
    f16*   w1t   = (f16*)(ws + OFF_W1T);
    f16*   w2t   = (f16*)(ws + OFF_W2T);
    float* outp  = (float*)d_out;

    // CSR build via bucket partition (no global scatter amplification)
    hipMemsetAsync(btot, 0, NBUCKET * sizeof(int), stream);
    k_bhist<<<P1GRID, 256, 0, stream>>>(dst, btot, blkh);
    k_bscan<<<1, 256, 0, stream>>>(btot, bst, gcur, offs);
    k_part1<<<P1GRID, 256, 0, stream>>>(src, dst, blkh, gcur, pairs);
    k_part2<<<NBUCKET, 256, 0, stream>>>(pairs, bst, offs, esrc);

    // conversions
    k_cvtX<<<6250, 256, 0, stream>>>(x, x16);
    k_cvtW<<<192, 256, 0, stream>>>(W1, w1t);
    k_cvtW<<<192, 256, 0, stream>>>(W2, w2t);
    hipMemsetAsync(a16 + (size_t)N_NODES * DIM, 0, (size_t)(N_PAD - N_NODES) * DIM * sizeof(f16), stream);
    hipMemsetAsync(b16 + (size_t)N_NODES * DIM, 0, (size_t)(N_PAD - N_NODES) * DIM * sizeof(f16), stream);

    // 3 GIN layers
    const f16* xin = x16;
    for (int l = 0; l < N_LAYERS; ++l) {
        f16* aggbuf = (l == 1) ? b16 : a16;
        k_agg<<<N_NODES / 4, 256, 0, stream>>>(xin, offs, esrc, aggbuf);
        k_mlp<<<N_PAD / BM, 256, 0, stream>>>(aggbuf, aggbuf,
                                              w1t + (size_t)l * DIM * DIM, b1 + (size_t)l * DIM,
                                              w2t + (size_t)l * DIM * DIM, b2 + (size_t)l * DIM);
        xin = aggbuf;
    }

    k_pool<<<N_GRAPHS, 128, 0, stream>>>(xin, batch, outp);
}

// Round 4
// 349.758 us; speedup vs baseline: 4.8186x; 1.0043x over previous
//
#include <hip/hip_runtime.h>
#include <hip/hip_bf16.h>
#include <stdint.h>

#define N_NODES  100000
#define N_PAD    100032          // padded to multiple of 64 for MLP tiles
#define N_EDGES  1600000
#define DIM      128
#define N_LAYERS 3
#define N_GRAPHS 2048

#define BSHIFT   9               // bucket = 512 consecutive dst nodes
#define NBUCKET  196             // ceil(N_NODES / 512)
#define P1CHUNK  8192
#define P1GRID   196             // ceil(N_EDGES / P1CHUNK)

typedef _Float16 f16;
typedef __attribute__((ext_vector_type(2))) _Float16 f16x2;
typedef __attribute__((ext_vector_type(4))) _Float16 f16x4;
typedef __attribute__((ext_vector_type(8))) _Float16 f16x8;
typedef __attribute__((ext_vector_type(4))) float f32x4;

#define MFMA16(a, b, c) __builtin_amdgcn_mfma_f32_16x16x32_f16((a), (b), (c), 0, 0, 0)

// ---------------- workspace layout (bytes, all 64B-aligned) ----------------
#define OFF_OFFS  0u             // (N_NODES+1) ints
#define OFF_BHT   400064u        // NBUCKET ints (bucket totals)
#define OFF_BST   400896u        // NBUCKET+1 ints (bucket starts)
#define OFF_GCUR  401728u        // NBUCKET ints (bucket cursors)
#define OFF_BLKH  402560u        // P1GRID*NBUCKET ints (per-block bucket hist)
#define OFF_ESRC  556288u        // N_EDGES ints
#define OFF_PAIR  6956288u       // N_EDGES uint2 (dst,src)
#define OFF_X16   19756288u      // N_PAD*DIM f16
#define OFF_A16   45364480u      // N_PAD*DIM f16
#define OFF_B16   70972672u      // N_PAD*DIM f16
#define OFF_W1T   96580864u      // 3*128*128 f16 ([l][n][k])
#define OFF_W2T   96679168u      // 3*128*128 f16
// end ~96.8 MB

// ---------------- CSR build: bucket partition ----------------

__global__ __launch_bounds__(256) void k_bhist(const int* __restrict__ dst,
                                               int* __restrict__ btot, int* __restrict__ blkh) {
    __shared__ int h[NBUCKET];
    int tid = threadIdx.x, b = blockIdx.x;
    if (tid < NBUCKET) h[tid] = 0;
    __syncthreads();
    int base = b * P1CHUNK;
    int n = min(P1CHUNK, N_EDGES - base);
    for (int i = tid; i < n; i += 256)
        atomicAdd(&h[dst[base + i] >> BSHIFT], 1);
    __syncthreads();
    if (tid < NBUCKET) {
        blkh[b * NBUCKET + tid] = h[tid];
        atomicAdd(&btot[tid], h[tid]);
    }
}

__global__ void k_bscan(const int* __restrict__ btot, int* __restrict__ bstart,
                        int* __restrict__ gcursor, int* __restrict__ offs) {
    __shared__ int s[NBUCKET + 1];
    if (threadIdx.x == 0) {
        int run = 0;
        for (int i = 0; i < NBUCKET; i++) { s[i] = run; run += btot[i]; }
        s[NBUCKET] = run;
    }
    __syncthreads();
    int t = threadIdx.x;
    if (t <= NBUCKET) bstart[t] = s[t];
    if (t < NBUCKET)  gcursor[t] = s[t];
    if (t == 0) offs[N_NODES] = N_EDGES;
}

__global__ __launch_bounds__(256) void k_part1(const int* __restrict__ src, const int* __restrict__ dst,
                                               const int* __restrict__ blkh, int* __restrict__ gcursor,
                                               uint2* __restrict__ pairs) {
    __shared__ int gbase[NBUCKET];
    __shared__ int cur[NBUCKET];
    int tid = threadIdx.x, b = blockIdx.x;
    if (tid < NBUCKET) {
        int h = blkh[b * NBUCKET + tid];
        gbase[tid] = atomicAdd(&gcursor[tid], h);
        cur[tid] = 0;
    }
    __syncthreads();
    int base = b * P1CHUNK;
    int n = min(P1CHUNK, N_EDGES - base);
    for (int i = tid; i < n; i += 256) {
        int d = dst[base + i], s = src[base + i];
        int bin = d >> BSHIFT;
        int slot = atomicAdd(&cur[bin], 1);
        uint2 p; p.x = (unsigned)d; p.y = (unsigned)s;
        pairs[gbase[bin] + slot] = p;     // lines exclusively written by this block
    }
}

__global__ __launch_bounds__(256) void k_part2(const uint2* __restrict__ pairs,
                                               const int* __restrict__ bstart,
                                               int* __restrict__ offs, int* __restrict__ esrc) {
    __shared__ int cnt[512];
    __shared__ int excl[512];
    __shared__ int sc[256];
    int t = threadIdx.x, b = blockIdx.x;
    int n0 = b << BSHIFT;
    int nn = min(512, N_NODES - n0);
    int e0 = bstart[b], e1 = bstart[b + 1];
    cnt[t] = 0; cnt[t + 256] = 0;
    __syncthreads();
    for (int i = e0 + t; i < e1; i += 256)
        atomicAdd(&cnt[pairs[i].x & 511], 1);
    __syncthreads();
    int a = cnt[2 * t], psum = a + cnt[2 * t + 1];
    sc[t] = psum;
    __syncthreads();
    for (int off = 1; off < 256; off <<= 1) {
        int v = (t >= off) ? sc[t - off] : 0;
        __syncthreads();
        sc[t] += v;
        __syncthreads();
    }
    int pairExcl = sc[t] - psum;
    excl[2 * t] = pairExcl;
    excl[2 * t + 1] = pairExcl + a;
    __syncthreads();
    for (int j = t; j < nn; j += 256) offs[n0 + j] = e0 + excl[j];
    __syncthreads();   // offs written before cursor mutation
    for (int i = e0 + t; i < e1; i += 256) {
        uint2 p = pairs[i];
        int pos = e0 + atomicAdd(&excl[p.x & 511], 1);
        esrc[pos] = (int)p.y;              // 32KB region, single block -> single XCD
    }
}

// ---------------- dtype conversion ----------------

__global__ void k_cvtX(const float* __restrict__ x, f16* __restrict__ o) {
    size_t i = ((size_t)blockIdx.x * 256 + threadIdx.x) * 8;
    float4 v0 = *(const float4*)&x[i];
    float4 v1 = *(const float4*)&x[i + 4];
    f16x8 h;
    h[0] = (f16)v0.x; h[1] = (f16)v0.y; h[2] = (f16)v0.z; h[3] = (f16)v0.w;
    h[4] = (f16)v1.x; h[5] = (f16)v1.y; h[6] = (f16)v1.z; h[7] = (f16)v1.w;
    *(f16x8*)&o[i] = h;
}

// W: [3][k][n] f32 -> Wt: [3][n][k] f16
__global__ void k_cvtW(const float* __restrict__ W, f16* __restrict__ Wt) {
    int t = blockIdx.x * 256 + threadIdx.x;
    int l = t >> 14;
    int kn = t & 16383;
    int k = kn >> 7, n = kn & 127;
    Wt[l * 16384 + n * 128 + k] = (f16)W[t];
}

// ---------------- fused layer: gather-agg -> LDS tile -> MLP -> global ----------------
// out = relu(relu((x_i + sum_j x_j) @ W1 + b1) @ W2 + b2)

#define BM 64
#define LDS_K 136    // padded row stride in f16 (272 B)

__global__ __launch_bounds__(256, 4) void k_fused(
    const f16* __restrict__ xin, f16* __restrict__ xout,
    const int* __restrict__ offs, const int* __restrict__ esrc,
    const f16* __restrict__ W1t, const float* __restrict__ b1,
    const f16* __restrict__ W2t, const float* __restrict__ b2)
{
    __shared__ __align__(16) f16 tile[BM * LDS_K];
    int tid  = threadIdx.x;
    int lane = tid & 63;
    int w    = tid >> 6;          // wave 0..3
    int fr   = lane & 15;         // 0..15
    int fg   = lane >> 4;         // 0..3
    int row0 = blockIdx.x * BM;

    // ---- gather phase: wave w covers nodes row0+w*16 .. +16; group fg owns 4 of them
    {
        int g = fg, c = fr;
        const f16x8* xr = (const f16x8*)xin;     // 16 x 16B chunks per row
        int srcLane = g << 4;
#pragma unroll
        for (int s_ = 0; s_ < 4; s_++) {
            int node = row0 + w * 16 + s_ * 4 + g;
            float acc[8];
            if (node < N_NODES) {
                int e0 = offs[node], e1 = offs[node + 1];
                f16x8 sv = xr[(size_t)node * 16 + c];
#pragma unroll
                for (int j = 0; j < 8; j++) acc[j] = (float)sv[j];
                for (int base = e0; base < e1; base += 16) {
                    int ncur = e1 - base; if (ncur > 16) ncur = 16;
                    int ev = esrc[base + (c < ncur ? c : ncur - 1)];   // coalesced prefetch
                    int k = 0;
                    for (; k + 4 <= ncur; k += 4) {
                        int s0 = __shfl(ev, srcLane + k);
                        int s1 = __shfl(ev, srcLane + k + 1);
                        int s2 = __shfl(ev, srcLane + k + 2);
                        int s3 = __shfl(ev, srcLane + k + 3);
                        f16x8 v0 = xr[(size_t)s0 * 16 + c];
                        f16x8 v1 = xr[(size_t)s1 * 16 + c];
                        f16x8 v2 = xr[(size_t)s2 * 16 + c];
                        f16x8 v3 = xr[(size_t)s3 * 16 + c];
#pragma unroll
                        for (int j = 0; j < 8; j++)
                            acc[j] += (float)v0[j] + (float)v1[j] + (float)v2[j] + (float)v3[j];
                    }
                    for (; k < ncur; k++) {
                        int s = __shfl(ev, srcLane + k);
                        f16x8 v = xr[(size_t)s * 16 + c];
#pragma unroll
                        for (int j = 0; j < 8; j++) acc[j] += (float)v[j];
                    }
                }
            } else {
#pragma unroll
                for (int j = 0; j < 8; j++) acc[j] = 0.f;
            }
            int r = w * 16 + s_ * 4 + g;
            f16x8 o;
#pragma unroll
            for (int j = 0; j < 8; j++) o[j] = (f16)acc[j];
            *(f16x8*)&tile[r * LDS_K + c * 8] = o;
        }
    }
    __syncthreads();

    // ---- GEMM1 (swapped operands -> H^T): lane holds H[n=w*32+nt*16+fg*4+r][m=mt*16+fr]
    f16x8 wf[2][4];
    float4 bv[2];
#pragma unroll
    for (int nt = 0; nt < 2; nt++) {
        int col = w * 32 + nt * 16 + fr;
#pragma unroll
        for (int ks = 0; ks < 4; ks++)
            wf[nt][ks] = *(const f16x8*)&W1t[col * DIM + ks * 32 + fg * 8];
        bv[nt] = *(const float4*)&b1[w * 32 + nt * 16 + fg * 4];
    }

    f32x4 acc[4][2];
#pragma unroll
    for (int mt = 0; mt < 4; mt++)
#pragma unroll
        for (int nt = 0; nt < 2; nt++) acc[mt][nt] = (f32x4){0.f, 0.f, 0.f, 0.f};

#pragma unroll
    for (int mt = 0; mt < 4; mt++)
#pragma unroll
        for (int ks = 0; ks < 4; ks++) {
            f16x8 a = *(const f16x8*)&tile[(mt * 16 + fr) * LDS_K + ks * 32 + fg * 8];
            acc[mt][0] = MFMA16(wf[0][ks], a, acc[mt][0]);
            acc[mt][1] = MFMA16(wf[1][ks], a, acc[mt][1]);
        }
    __syncthreads();   // all X reads done before overwriting tile with H

    // H epilogue: relu(acc+b1), 8B vector writes to tile[node][feature]
#pragma unroll
    for (int mt = 0; mt < 4; mt++)
#pragma unroll
        for (int nt = 0; nt < 2; nt++) {
            f16x4 hv;
            hv[0] = (f16)fmaxf(acc[mt][nt][0] + bv[nt].x, 0.f);
            hv[1] = (f16)fmaxf(acc[mt][nt][1] + bv[nt].y, 0.f);
            hv[2] = (f16)fmaxf(acc[mt][nt][2] + bv[nt].z, 0.f);
            hv[3] = (f16)fmaxf(acc[mt][nt][3] + bv[nt].w, 0.f);
            *(f16x4*)&tile[(mt * 16 + fr) * LDS_K + w * 32 + nt * 16 + fg * 4] = hv;
        }

    // reload fragments with W2/b2 (L2-hot), reuse registers
#pragma unroll
    for (int nt = 0; nt < 2; nt++) {
        int col = w * 32 + nt * 16 + fr;
#pragma unroll
        for (int ks = 0; ks < 4; ks++)
            wf[nt][ks] = *(const f16x8*)&W2t[col * DIM + ks * 32 + fg * 8];
        bv[nt] = *(const float4*)&b2[w * 32 + nt * 16 + fg * 4];
    }
    __syncthreads();   // H fully written

    // ---- GEMM2 (swapped): lane holds OUT[n][m], store 8B direct to global
#pragma unroll
    for (int mt = 0; mt < 4; mt++)
#pragma unroll
        for (int nt = 0; nt < 2; nt++) acc[mt][nt] = (f32x4){0.f, 0.f, 0.f, 0.f};

#pragma unroll
    for (int mt = 0; mt < 4; mt++)
#pragma unroll
        for (int ks = 0; ks < 4; ks++) {
            f16x8 a = *(const f16x8*)&tile[(mt * 16 + fr) * LDS_K + ks * 32 + fg * 8];
            acc[mt][0] = MFMA16(wf[0][ks], a, acc[mt][0]);
            acc[mt][1] = MFMA16(wf[1][ks], a, acc[mt][1]);
        }

#pragma unroll
    for (int mt = 0; mt < 4; mt++)
#pragma unroll
        for (int nt = 0; nt < 2; nt++) {
            f16x4 ov;
            ov[0] = (f16)fmaxf(acc[mt][nt][0] + bv[nt].x, 0.f);
            ov[1] = (f16)fmaxf(acc[mt][nt][1] + bv[nt].y, 0.f);
            ov[2] = (f16)fmaxf(acc[mt][nt][2] + bv[nt].z, 0.f);
            ov[3] = (f16)fmaxf(acc[mt][nt][3] + bv[nt].w, 0.f);
            *(f16x4*)&xout[(size_t)(row0 + mt * 16 + fr) * DIM + w * 32 + nt * 16 + fg * 4] = ov;
        }
}

// ---------------- pool ----------------

__global__ void k_pool(const f16* __restrict__ xf, const int* __restrict__ batch,
                       float* __restrict__ out) {
    int g = blockIdx.x;
    int d = threadIdx.x;
    int lo = 0, hi = N_NODES;
    while (lo < hi) { int m = (lo + hi) >> 1; if (batch[m] < g) lo = m + 1; else hi = m; }
    int start = lo;
    hi = N_NODES;
    while (lo < hi) { int m = (lo + hi) >> 1; if (batch[m] <= g) lo = m + 1; else hi = m; }
    int end = lo;
    float acc = 0.f;
    for (int i = start; i < end; i++) acc += (float)xf[(size_t)i * DIM + d];
    float cntf = (float)(end - start);
    out[(size_t)g * DIM + d] = acc / fmaxf(cntf, 1.f);
}

// ---------------- launch ----------------

extern "C" void kernel_launch(void* const* d_in, const int* in_sizes, int n_in,
                              void* d_out, int out_size, void* d_ws, size_t ws_size,
                              hipStream_t stream) {
    const float* x     = (const float*)d_in[0];
    const int*   ei    = (const int*)d_in[1];
    const int*   batch = (const int*)d_in[2];
    const float* W1    = (const float*)d_in[3];
    const float* b1    = (const float*)d_in[4];
    const float* W2    = (const float*)d_in[5];
    const float* b2    = (const float*)d_in[6];
    const int* src = ei;
    const int* dst = ei + N_EDGES;

    char* ws = (char*)d_ws;
    int*   offs  = (int*)(ws + OFF_OFFS);
    int*   btot  = (int*)(ws + OFF_BHT);
    int*   bst   = (int*)(ws + OFF_BST);
    int*   gcur  = (int*)(ws + OFF_GCUR);
    int*   blkh  = (int*)(ws + OFF_BLKH);
    int*   esrc  = (int*)(ws + OFF_ESRC);
    uint2* pairs = (uint2*)(ws + OFF_PAIR);
    f16*   x16   = (f16*)(ws + OFF_X16);
    f16*   a16   = (f16*)(ws + OFF_A16);
    f16*   b16   = (f16*)(ws + OFF_B16);
    f16*   w1t   = (f16*)(ws + OFF_W1T);
    f16*   w2t   = (f16*)(ws + OFF_W2T);
    float* outp  = (float*)d_out;

    // CSR build via bucket partition
    hipMemsetAsync(btot, 0, NBUCKET * sizeof(int), stream);
    k_bhist<<<P1GRID, 256, 0, stream>>>(dst, btot, blkh);
    k_bscan<<<1, 256, 0, stream>>>(btot, bst, gcur, offs);
    k_part1<<<P1GRID, 256, 0, stream>>>(src, dst, blkh, gcur, pairs);
    k_part2<<<NBUCKET, 256, 0, stream>>>(pairs, bst, offs, esrc);

    // conversions
    k_cvtX<<<6250, 256, 0, stream>>>(x, x16);
    k_cvtW<<<192, 256, 0, stream>>>(W1, w1t);
    k_cvtW<<<192, 256, 0, stream>>>(W2, w2t);

    // 3 fused GIN layers (gather+MLP)
    const f16* xin = x16;
    for (int l = 0; l < N_LAYERS; ++l) {
        f16* xoutb = (l == 1) ? b16 : a16;   // x16 -> A -> B -> A
        k_fused<<<N_PAD / BM, 256, 0, stream>>>(xin, xoutb, offs, esrc,
                                                w1t + (size_t)l * DIM * DIM, b1 + (size_t)l * DIM,
                                                w2t + (size_t)l * DIM * DIM, b2 + (size_t)l * DIM);
        xin = xoutb;
    }

    k_pool<<<N_GRAPHS, 128, 0, stream>>>(xin, batch, outp);
}